// Round 7
// baseline (190.793 us; speedup 1.0000x reference)
//
#include <hip/hip_runtime.h>
#include <hip/hip_fp16.h>

// ---------------- types ----------------
typedef __attribute__((ext_vector_type(8))) short short8;
typedef __attribute__((ext_vector_type(4))) float f32x4;

#define GLOBAL_AS __attribute__((address_space(1)))
#define LDS_AS __attribute__((address_space(3)))

static __device__ __forceinline__ void gload16(const void* g, void* l) {
    __builtin_amdgcn_global_load_lds((const GLOBAL_AS void*)g, (LDS_AS void*)l, 16, 0, 0);
}

#define SBAR() __builtin_amdgcn_s_barrier()
#define WAITVM(N) asm volatile("s_waitcnt vmcnt(" #N ")" ::: "memory")
#define WAITLGKM0() do { asm volatile("s_waitcnt lgkmcnt(0)" ::: "memory"); \
                         __builtin_amdgcn_sched_barrier(0); } while (0)

// float -> bf16 RNE via bit trick
static __device__ __forceinline__ unsigned short f2bf(float f) {
    union { float f; unsigned u; } v; v.f = f;
    unsigned r = v.u + 0x7FFFu + ((v.u >> 16) & 1u);
    return (unsigned short)(r >> 16);
}

// Detect storage dtype of ortho_vals (round-1 finding: harness delivers fp16
// refs as fp32). Score fp32/fp16/bf16 interpretations of the first 192 values
// against the known outlier range |v| in [1e-5, 0.5]. Deterministic.
static __device__ int detect_vals_kind(const void* vals) {  // 0=f32 1=f16 2=bf16
    const float* f = (const float*)vals;
    const unsigned short* h = (const unsigned short*)vals;
    int s0 = 0, s1 = 0, s2 = 0;
    for (int i = 0; i < 192; ++i) {
        float a0 = fabsf(f[i]);
        if (a0 >= 1e-5f && a0 <= 0.5f) s0++;
        float a1 = fabsf(__half2float(((const __half*)vals)[i]));
        if (a1 >= 1e-5f && a1 <= 0.5f) s1++;
        union { unsigned u; float fv; } c; c.u = ((unsigned)h[i]) << 16;
        float a2 = fabsf(c.fv);
        if (a2 >= 1e-5f && a2 <= 0.5f) s2++;
    }
    if (s0 >= s1 && s0 >= s2) return 0;
    if (s1 >= s2) return 1;
    return 2;
}

// ---------------- kernel 1: fused prep ----------------
// blocks [0,4096): dequant W row -> bf16 (int4 + scale + CSR outliers)
// blocks [4096,6144): x fp32 -> bf16 cast (grid-stride over 2M short8)
__global__ __launch_bounds__(256) void prep_kernel(
    const int* __restrict__ packed,      // [4096][2048] one byte value per int
    const float* __restrict__ scales,    // [4096]
    const void* __restrict__ vals,       // [nnz] dtype auto-detected
    const int* __restrict__ idxs,        // [nnz]
    const int* __restrict__ ptr,         // [4097]
    uint4* __restrict__ Wb4,             // [4096][512] uint4 = 8 bf16
    const float* __restrict__ x,
    unsigned short* __restrict__ xb)
{
    if (blockIdx.x >= 4096) {
        const int n8 = (4096 * 4096) / 8;
        const int stride = 2048 * 256;
        for (int j = (blockIdx.x - 4096) * 256 + threadIdx.x; j < n8; j += stride) {
            const float4 a = ((const float4*)x)[2 * (size_t)j];
            const float4 b = ((const float4*)x)[2 * (size_t)j + 1];
            short8 o;
            o[0] = (short)f2bf(a.x); o[1] = (short)f2bf(a.y);
            o[2] = (short)f2bf(a.z); o[3] = (short)f2bf(a.w);
            o[4] = (short)f2bf(b.x); o[5] = (short)f2bf(b.y);
            o[6] = (short)f2bf(b.z); o[7] = (short)f2bf(b.w);
            *(short8*)(xb + 8 * (size_t)j) = o;
        }
        return;
    }
    __shared__ float sp[4096];
    __shared__ int skind;
    const int row = blockIdx.x;
    float4* sp4 = (float4*)sp;
    const float4 z4 = make_float4(0.f, 0.f, 0.f, 0.f);
    for (int i = threadIdx.x; i < 1024; i += 256) sp4[i] = z4;
    if (threadIdx.x == 0) skind = detect_vals_kind(vals);
    __syncthreads();
    const int kind = skind;
    const int s = ptr[row], e = ptr[row + 1];
    if (kind == 0) {
        const float* vf = (const float*)vals;
        for (int i = s + threadIdx.x; i < e; i += 256) atomicAdd(&sp[idxs[i]], vf[i]);
    } else if (kind == 1) {
        const __half* vh = (const __half*)vals;
        for (int i = s + threadIdx.x; i < e; i += 256) atomicAdd(&sp[idxs[i]], __half2float(vh[i]));
    } else {
        const unsigned short* vb = (const unsigned short*)vals;
        for (int i = s + threadIdx.x; i < e; i += 256) {
            union { unsigned u; float fv; } c; c.u = ((unsigned)vb[i]) << 16;
            atomicAdd(&sp[idxs[i]], c.fv);
        }
    }
    __syncthreads();
    const float sc = scales[row];
    const int4* prow4 = (const int4*)(packed + (size_t)row * 2048);
    uint4* wrow4 = Wb4 + (size_t)row * 512;
    for (int j = threadIdx.x; j < 512; j += 256) {
        const int4 p = prow4[j];
        const float* spc = sp + 8 * j;
        uint4 o;
        o.x = (unsigned)f2bf((float)((p.x & 0xF) - 8) * sc + spc[0]) |
              ((unsigned)f2bf((float)(((p.x >> 4) & 0xF) - 8) * sc + spc[1]) << 16);
        o.y = (unsigned)f2bf((float)((p.y & 0xF) - 8) * sc + spc[2]) |
              ((unsigned)f2bf((float)(((p.y >> 4) & 0xF) - 8) * sc + spc[3]) << 16);
        o.z = (unsigned)f2bf((float)((p.z & 0xF) - 8) * sc + spc[4]) |
              ((unsigned)f2bf((float)(((p.z >> 4) & 0xF) - 8) * sc + spc[5]) << 16);
        o.w = (unsigned)f2bf((float)((p.w & 0xF) - 8) * sc + spc[6]) |
              ((unsigned)f2bf((float)(((p.w >> 4) & 0xF) - 8) * sc + spc[7]) << 16);
        wrow4[j] = o;
    }
}

// ---------------- kernel 2: 256x256 tile, BK=32, 3-buffer, phase-paced GEMM ----------------
// C[M,N] = A[M,K] * B[N,K]^T, 16x16x32 bf16 MFMA (reverted: r6's 32x32 regressed).
// Round-7 structure (m201 pacing + clean depth):
//  - BK=32, 3 LDS buffers (96KB): tile t+2 staged while computing tile t ->
//    every gload has ~2 K-tiles (>2000cyc) of cover before its WAITVM.
//  - 2 phases per K-tile, each: {ds_reads; 2 gload_lds; SBAR; lgkmcnt(0)+
//    sched_barrier; setprio(1); 16 MFMA; setprio(0); SBAR} -- barrier pacing
//    creates wave role-split so ds_reads of one wave overlap MFMA of the other.
//  - Counted WAITVM(4) once per tile at close (waits only 2-tile-old loads;
//    vmcnt(0) only for the last tiles where nothing newer is in flight).
//  - 64B LDS rows: swizzle seg^=row&3 via pre-swizzled global source + XOR'd
//    read offset; every 16-lane beat spans all 32 banks at 2/bank (free).
// Hazard ledger: stage target buf[(t+2)%3]=buf[(t-1)%3]; tile t-1's reads are
// lgkm-waited before its last MFMA, which precedes its closing SBAR, which
// precedes tile t's stage issues. Reads of buf[cur] follow the closing
// SBAR+WAITVM of tile t-1 which guarantees tile t's loads landed chip-wide.
__global__ __launch_bounds__(512, 2) void gemm_bt_kernel(
    const unsigned short* __restrict__ A,   // bf16 bits, M x K
    const unsigned short* __restrict__ B,   // bf16 bits, N x K
    float* __restrict__ C)                  // fp32, M x N
{
    constexpr int K = 4096;
    constexpr int N = 4096;
    constexpr int NT = K / 32;   // 128 K-tiles
    __shared__ __attribute__((aligned(128))) char smem[98304]; // 3 x [A 16KB | B 16KB]

    const int tid = threadIdx.x;
    const int lane = tid & 63;
    const int wv = tid >> 6;              // 0..7
    const int bid = (blockIdx.x & 7) * 32 + (blockIdx.x >> 3);  // bijective XCD swizzle
    const int bm = bid >> 4;              // 16 M-tiles
    const int bn = bid & 15;              // 16 N-tiles

    // ---- staging: one gload16 round (512 thr x 16B = 8KB) = 128 rows x 64B ----
    const int grow = tid >> 2;                          // 0..127 row within round
    const int sg4 = (tid & 3) ^ (grow & 3);             // pre-swizzled 16B segment
    const unsigned short* ag = A + (size_t)(bm * 256 + grow) * K + sg4 * 8;
    const unsigned short* bg = B + (size_t)(bn * 256 + grow) * K + sg4 * 8;
    char* ldsw = smem + wv * 1024;                      // wave-uniform base

    // rounds: 0,1 = A rows 0-127 / 128-255 ; 2,3 = B rows 0-127 / 128-255
#define STAGE(R, KT, BUF)                                                              \
    {                                                                                  \
        if ((R) < 2)                                                                   \
            gload16(ag + (size_t)((R) * 128) * K + (KT),                               \
                    ldsw + (BUF) * 32768 + (R) * 8192);                                \
        else                                                                           \
            gload16(bg + (size_t)(((R) - 2) * 128) * K + (KT),                         \
                    ldsw + (BUF) * 32768 + 16384 + ((R) - 2) * 8192);                  \
    }

    // ---- fragment read geometry (16x16x32): lane reads row (base+lane&15),
    //      16B k-segment (lane>>4), XOR row&3 (== lane&3 since bases %16==0) ----
    const int wr = wv >> 2, wc = wv & 3;                // 2x4 wave grid
    const int rowa = wr * 128 + (lane & 15);            // + mh*64 + m*16
    const int rowb = wc * 64 + (lane & 15);             // + n*16
    const int sr = (((lane >> 4) ^ (lane & 3)) << 4);   // swizzled byte seg

#define LDA4(DST, MH, BUF)                                                             \
    {                                                                                  \
        _Pragma("unroll") for (int m = 0; m < 4; ++m) {                                \
            const int row_ = rowa + (MH) * 64 + m * 16;                                \
            DST[m] = *(const short8*)(smem + (BUF) * 32768 + row_ * 64 + sr);          \
        }                                                                              \
    }
#define LDB4(DST, BUF)                                                                 \
    {                                                                                  \
        _Pragma("unroll") for (int n = 0; n < 4; ++n) {                                \
            const int row_ = rowb + n * 16;                                            \
            DST[n] = *(const short8*)(smem + (BUF) * 32768 + 16384 + row_ * 64 + sr);  \
        }                                                                              \
    }
#define MFMA16(AF, BF, MH)                                                             \
    {                                                                                  \
        __builtin_amdgcn_s_setprio(1);                                                 \
        _Pragma("unroll") for (int m = 0; m < 4; ++m)                                  \
            _Pragma("unroll") for (int n = 0; n < 4; ++n)                              \
                acc[(MH) * 4 + m][n] = __builtin_amdgcn_mfma_f32_16x16x32_bf16(        \
                    AF[m], BF[n], acc[(MH) * 4 + m][n], 0, 0, 0);                      \
        __builtin_amdgcn_s_setprio(0);                                                 \
    }

    f32x4 acc[8][4];
#pragma unroll
    for (int m = 0; m < 8; ++m)
#pragma unroll
        for (int n = 0; n < 4; ++n) acc[m][n] = (f32x4)0.0f;

    // ---- prologue: stage tiles 0 and 1 (issue order = vmcnt order) ----
#pragma unroll
    for (int r = 0; r < 4; ++r) STAGE(r, 0, 0);
#pragma unroll
    for (int r = 0; r < 4; ++r) STAGE(r, 32, 1);
    WAITVM(4);   // tile 0's rounds done; tile 1's 4 remain in flight
    SBAR();

    int cur = 0;
    for (int t = 0; t < NT; ++t) {
        int sb = cur + 2; if (sb >= 3) sb -= 3;
        const int kt2 = (t + 2) * 32;
        const bool st = (t + 2 < NT);
        __builtin_amdgcn_sched_barrier(0);

        short8 af0[4], af1[4], bf[4];
        // ---- phase 0: quadrant mh=0 ----
        LDA4(af0, 0, cur); LDB4(bf, cur);
        if (st) { STAGE(0, kt2, sb); STAGE(1, kt2, sb); }
        SBAR();
        WAITLGKM0();
        MFMA16(af0, bf, 0);
        SBAR();
        // ---- phase 1: quadrant mh=1 (B reused in regs) ----
        LDA4(af1, 1, cur);
        if (st) { STAGE(2, kt2, sb); STAGE(3, kt2, sb); }
        SBAR();
        WAITLGKM0();
        MFMA16(af1, bf, 1);
        // ---- tile close: ensure tile t+1's loads landed; keep t+2's in flight ----
        if (st) { WAITVM(4); } else { WAITVM(0); }
        SBAR();
        cur = cur + 1; if (cur == 3) cur = 0;
    }

    // ---- epilogue: C/D layout col=lane&15, row=(lane>>4)*4+reg ----
    const int crow0 = bm * 256 + wr * 128 + (lane >> 4) * 4;
    const int ccol0 = bn * 256 + wc * 64 + (lane & 15);
#pragma unroll
    for (int m = 0; m < 8; ++m)
#pragma unroll
        for (int n = 0; n < 4; ++n)
#pragma unroll
            for (int r = 0; r < 4; ++r)
                C[(size_t)(crow0 + m * 16 + r) * N + ccol0 + n * 16] = acc[m][n][r];
}

// ---------------- launch ----------------
extern "C" void kernel_launch(void* const* d_in, const int* in_sizes, int n_in,
                              void* d_out, int out_size, void* d_ws, size_t ws_size,
                              hipStream_t stream) {
    const float* x        = (const float*)d_in[0];
    const int* packed     = (const int*)d_in[1];
    const float* scales   = (const float*)d_in[2];
    const void* vals      = (const void*)d_in[3];
    const int* idxs       = (const int*)d_in[4];
    const int* ptr        = (const int*)d_in[5];
    float* out            = (float*)d_out;

    unsigned short* Wb = (unsigned short*)d_ws;            // 4096*4096 bf16 = 32 MB
    unsigned short* Xb = Wb + (size_t)4096 * 4096;         // next 32 MB

    prep_kernel<<<6144, 256, 0, stream>>>(packed, scales, vals, idxs, ptr,
                                          (uint4*)Wb, x, Xb);
    gemm_bt_kernel<<<256, 512, 0, stream>>>(Xb, Wb, out);
}

// Round 8
// 148.527 us; speedup vs baseline: 1.2846x; 1.2846x over previous
//
#include <hip/hip_runtime.h>
#include <hip/hip_fp16.h>

// ---------------- types ----------------
typedef __attribute__((ext_vector_type(8))) short short8;
typedef __attribute__((ext_vector_type(4))) float f32x4;

#define GLOBAL_AS __attribute__((address_space(1)))
#define LDS_AS __attribute__((address_space(3)))

static __device__ __forceinline__ void gload16(const void* g, void* l) {
    __builtin_amdgcn_global_load_lds((const GLOBAL_AS void*)g, (LDS_AS void*)l, 16, 0, 0);
}

#define SBAR() __builtin_amdgcn_s_barrier()
#define WAITVM(N) asm volatile("s_waitcnt vmcnt(" #N ")" ::: "memory")

// float -> bf16 RNE via bit trick
static __device__ __forceinline__ unsigned short f2bf(float f) {
    union { float f; unsigned u; } v; v.f = f;
    unsigned r = v.u + 0x7FFFu + ((v.u >> 16) & 1u);
    return (unsigned short)(r >> 16);
}

// ---------------- kernel 1: fused prep ----------------
// blocks [0,4096): dequant W row -> bf16 (int4 + scale + CSR outliers)
// blocks [4096,6144): x fp32 -> bf16 cast (grid-stride over 2M short8)
// ortho_vals dtype detected in parallel (3 waves score fp32/fp16/bf16
// interpretations of the first 192 values vs |v| in [1e-5,0.5]; round-1
// finding: harness delivers fp16 refs as fp32). Deterministic.
__global__ __launch_bounds__(256) void prep_kernel(
    const int* __restrict__ packed,      // [4096][2048] one byte value per int
    const float* __restrict__ scales,    // [4096]
    const void* __restrict__ vals,       // [nnz] dtype auto-detected
    const int* __restrict__ idxs,        // [nnz]
    const int* __restrict__ ptr,         // [4097]
    uint4* __restrict__ Wb4,             // [4096][512] uint4 = 8 bf16
    const float* __restrict__ x,
    unsigned short* __restrict__ xb)
{
    if (blockIdx.x >= 4096) {
        const int n8 = (4096 * 4096) / 8;
        const int stride = 2048 * 256;
        for (int j = (blockIdx.x - 4096) * 256 + threadIdx.x; j < n8; j += stride) {
            const float4 a = ((const float4*)x)[2 * (size_t)j];
            const float4 b = ((const float4*)x)[2 * (size_t)j + 1];
            short8 o;
            o[0] = (short)f2bf(a.x); o[1] = (short)f2bf(a.y);
            o[2] = (short)f2bf(a.z); o[3] = (short)f2bf(a.w);
            o[4] = (short)f2bf(b.x); o[5] = (short)f2bf(b.y);
            o[6] = (short)f2bf(b.z); o[7] = (short)f2bf(b.w);
            *(short8*)(xb + 8 * (size_t)j) = o;
        }
        return;
    }
    __shared__ float sp[4096];
    __shared__ int sc[3];
    const int row = blockIdx.x;
    float4* sp4 = (float4*)sp;
    const float4 z4 = make_float4(0.f, 0.f, 0.f, 0.f);
    for (int i = threadIdx.x; i < 1024; i += 256) sp4[i] = z4;

    // parallel dtype detect: wave w scores interpretation w over i=lane,lane+64,lane+128
    {
        const int wvp = threadIdx.x >> 6, ln = threadIdx.x & 63;
        if (wvp < 3) {
            int c = 0;
            for (int i = ln; i < 192; i += 64) {
                float a;
                if (wvp == 0) a = fabsf(((const float*)vals)[i]);
                else if (wvp == 1) a = fabsf(__half2float(((const __half*)vals)[i]));
                else { union { unsigned u; float fv; } cc;
                       cc.u = ((unsigned)((const unsigned short*)vals)[i]) << 16;
                       a = fabsf(cc.fv); }
                c += (a >= 1e-5f && a <= 0.5f) ? 1 : 0;
            }
            for (int o = 32; o; o >>= 1) c += __shfl_down(c, o);
            if (ln == 0) sc[wvp] = c;
        }
    }
    __syncthreads();
    const int kind = (sc[0] >= sc[1] && sc[0] >= sc[2]) ? 0 : (sc[1] >= sc[2] ? 1 : 2);
    const int s = ptr[row], e = ptr[row + 1];
    if (kind == 0) {
        const float* vf = (const float*)vals;
        for (int i = s + threadIdx.x; i < e; i += 256) atomicAdd(&sp[idxs[i]], vf[i]);
    } else if (kind == 1) {
        const __half* vh = (const __half*)vals;
        for (int i = s + threadIdx.x; i < e; i += 256) atomicAdd(&sp[idxs[i]], __half2float(vh[i]));
    } else {
        const unsigned short* vb = (const unsigned short*)vals;
        for (int i = s + threadIdx.x; i < e; i += 256) {
            union { unsigned u; float fv; } c; c.u = ((unsigned)vb[i]) << 16;
            atomicAdd(&sp[idxs[i]], c.fv);
        }
    }
    __syncthreads();
    const float sc_ = scales[row];
    const int4* prow4 = (const int4*)(packed + (size_t)row * 2048);
    uint4* wrow4 = Wb4 + (size_t)row * 512;
    for (int j = threadIdx.x; j < 512; j += 256) {
        const int4 p = prow4[j];
        const float* spc = sp + 8 * j;
        uint4 o;
        o.x = (unsigned)f2bf((float)((p.x & 0xF) - 8) * sc_ + spc[0]) |
              ((unsigned)f2bf((float)(((p.x >> 4) & 0xF) - 8) * sc_ + spc[1]) << 16);
        o.y = (unsigned)f2bf((float)((p.y & 0xF) - 8) * sc_ + spc[2]) |
              ((unsigned)f2bf((float)(((p.y >> 4) & 0xF) - 8) * sc_ + spc[3]) << 16);
        o.z = (unsigned)f2bf((float)((p.z & 0xF) - 8) * sc_ + spc[4]) |
              ((unsigned)f2bf((float)(((p.z >> 4) & 0xF) - 8) * sc_ + spc[5]) << 16);
        o.w = (unsigned)f2bf((float)((p.w & 0xF) - 8) * sc_ + spc[6]) |
              ((unsigned)f2bf((float)(((p.w >> 4) & 0xF) - 8) * sc_ + spc[7]) << 16);
        wrow4[j] = o;
    }
}

// ---------------- kernel 2: 256x256 tile, BK=64, 5-slot circular LDS GEMM ----------------
// C[M,N] = A[M,K]*B[N,K]^T, 16x16x32 bf16 MFMA, 8 waves (2Mx4N), wave 128x64.
// Round-8: r5's free-running schedule + 5 x 32KB LDS slots (160KB, full CU pool).
//   A(t)@slot(2t)%5, B(t)@(2t+1)%5. During tile t's phases: issue B(t+1)
//   (P0,P1) then A(t+2) (P2,P3). Boundary: ONE WAITVM(4) (leaves A(t+1) in
//   flight) + ONE SBAR per tile. Every waited load is >=3 phases (~1800cyc)
//   old -> no exposed HBM latency (r5's rounds-6,7 stall eliminated, and one
//   barrier per tile instead of two).
// Hazard ledger: B(t+1) writes A(t-1)'s slot, A(t+2) writes B(t-1)'s slot --
//   both freed (reads lgkm-consumed) before SBAR(t), and writes issue after
//   SBAR(t) (sched_barrier pins). Reads of A(t),B(t) follow WAITVM(4)+SBAR.
// Swizzle identical to r5 (measured 0 conflicts): 128B rows, pre-swizzled
// global source seg^(row&7), read seg ((kk*4+khw)^(lane&7)).
__global__ __launch_bounds__(512, 2) void gemm_bt_kernel(
    const unsigned short* __restrict__ A,   // bf16 bits, M x K
    const unsigned short* __restrict__ B,   // bf16 bits, N x K
    float* __restrict__ C)                  // fp32, M x N
{
    constexpr int K = 4096;
    constexpr int N = 4096;
    constexpr int NT = K / 64;   // 64 K-tiles
    __shared__ __attribute__((aligned(128))) char smem[163840]; // 5 x 32KB slots

    const int tid = threadIdx.x;
    const int lane = tid & 63;
    const int wv = tid >> 6;              // 0..7
    const int bid = (blockIdx.x & 7) * 32 + (blockIdx.x >> 3);  // bijective XCD swizzle
    const int bm = bid >> 4;              // 16 M-tiles
    const int bn = bid & 15;              // 16 N-tiles

    // ---- staging: one gload16 round (512 thr x 16B = 8KB) = 64 rows x 128B ----
    const int grow = tid >> 3;                          // 0..63 row within round
    const int sg = (tid & 7) ^ (grow & 7);              // pre-swizzled 16B segment
    const unsigned short* ag = A + (size_t)(bm * 256 + grow) * K + sg * 8;
    const unsigned short* bg = B + (size_t)(bn * 256 + grow) * K + sg * 8;

    // round R covers rows R*64..R*64+63 of the operand tile; wave writes its
    // 8-row slice (1KB) of each round.
#define STA(R, KT, SLOT)                                                               \
    gload16(ag + (size_t)((R) * 64) * K + (KT),                                        \
            smem + (SLOT) * 32768 + (R) * 8192 + wv * 1024);
#define STB(R, KT, SLOT)                                                               \
    gload16(bg + (size_t)((R) * 64) * K + (KT),                                        \
            smem + (SLOT) * 32768 + (R) * 8192 + wv * 1024);

    // ---- fragment read geometry ----
    const int wr = wv >> 2, wc = wv & 3;                // 2x4 wave grid
    const int rowa = wr * 128 + (lane & 15);            // + mh*64 + m*16
    const int rowb = wc * 64 + (lane & 15);             // + n*16
    const int khw = lane >> 4;                          // 0..3
    const int rx = lane & 7;                            // == row&7 (bases mult of 16)

#define LDA4(DST, MH, KK, SLOT)                                                        \
    {                                                                                  \
        _Pragma("unroll") for (int m = 0; m < 4; ++m) {                                \
            const int row_ = rowa + (MH) * 64 + m * 16;                                \
            DST[m] = *(const short8*)(smem + (SLOT) * 32768 + row_ * 128 +             \
                                      (((((KK) << 2) + khw) ^ rx) << 4));              \
        }                                                                              \
    }
#define LDB4(DST, KK, SLOT)                                                            \
    {                                                                                  \
        _Pragma("unroll") for (int n = 0; n < 4; ++n) {                                \
            const int row_ = rowb + n * 16;                                            \
            DST[n] = *(const short8*)(smem + (SLOT) * 32768 + row_ * 128 +             \
                                      (((((KK) << 2) + khw) ^ rx) << 4));              \
        }                                                                              \
    }
#define MFMA16(AF, BF, MH)                                                             \
    {                                                                                  \
        __builtin_amdgcn_s_setprio(1);                                                 \
        _Pragma("unroll") for (int m = 0; m < 4; ++m)                                  \
            _Pragma("unroll") for (int n = 0; n < 4; ++n)                              \
                acc[(MH) * 4 + m][n] = __builtin_amdgcn_mfma_f32_16x16x32_bf16(        \
                    AF[m], BF[n], acc[(MH) * 4 + m][n], 0, 0, 0);                      \
        __builtin_amdgcn_s_setprio(0);                                                 \
    }

    f32x4 acc[8][4];
#pragma unroll
    for (int m = 0; m < 8; ++m)
#pragma unroll
        for (int n = 0; n < 4; ++n) acc[m][n] = (f32x4)0.0f;

    // ---- prologue: queue = [A(0)@s0, B(0)@s1, A(1)@s2] (12 loads) ----
#pragma unroll
    for (int r = 0; r < 4; ++r) STA(r, 0, 0);
#pragma unroll
    for (int r = 0; r < 4; ++r) STB(r, 0, 1);
#pragma unroll
    for (int r = 0; r < 4; ++r) STA(r, 64, 2);

    int sA = 0, sB = 1, sB1 = 3, sA2 = 4;  // (2t)%5, (2t+1)%5, (2t+3)%5, (2t+4)%5
    for (int t = 0; t < NT; ++t) {
        const int ktn = (t + 1) * 64;
        const int ktn2 = (t + 2) * 64;
        const bool s1 = (t + 1 < NT), s2 = (t + 2 < NT);
        // boundary: wait A(t),B(t) (>=3 phases old); A(t+1) stays in flight.
        if (s1) { WAITVM(4); } else { WAITVM(0); }
        SBAR();
        __builtin_amdgcn_sched_barrier(0);

        short8 af0[4], af1[4], bf0[4], bf1[4];
        LDA4(af0, 0, 0, sA); LDB4(bf0, 0, sB);
        if (s1) { STB(0, ktn, sB1); STB(1, ktn, sB1); }
        MFMA16(af0, bf0, 0);
        LDA4(af1, 1, 0, sA);
        if (s1) { STB(2, ktn, sB1); STB(3, ktn, sB1); }
        MFMA16(af1, bf0, 1);
        LDA4(af0, 0, 1, sA); LDB4(bf1, 1, sB);
        if (s2) { STA(0, ktn2, sA2); STA(1, ktn2, sA2); }
        MFMA16(af0, bf1, 0);
        LDA4(af1, 1, 1, sA);
        if (s2) { STA(2, ktn2, sA2); STA(3, ktn2, sA2); }
        MFMA16(af1, bf1, 1);

        sA += 2; if (sA >= 5) sA -= 5;
        sB += 2; if (sB >= 5) sB -= 5;
        sB1 += 2; if (sB1 >= 5) sB1 -= 5;
        sA2 += 2; if (sA2 >= 5) sA2 -= 5;
    }

    // ---- epilogue: C/D layout col=lane&15, row=(lane>>4)*4+reg ----
    const int crow0 = bm * 256 + wr * 128 + (lane >> 4) * 4;
    const int ccol0 = bn * 256 + wc * 64 + (lane & 15);
#pragma unroll
    for (int m = 0; m < 8; ++m)
#pragma unroll
        for (int n = 0; n < 4; ++n)
#pragma unroll
            for (int r = 0; r < 4; ++r)
                C[(size_t)(crow0 + m * 16 + r) * N + ccol0 + n * 16] = acc[m][n][r];
}

// ---------------- launch ----------------
extern "C" void kernel_launch(void* const* d_in, const int* in_sizes, int n_in,
                              void* d_out, int out_size, void* d_ws, size_t ws_size,
                              hipStream_t stream) {
    const float* x        = (const float*)d_in[0];
    const int* packed     = (const int*)d_in[1];
    const float* scales   = (const float*)d_in[2];
    const void* vals      = (const void*)d_in[3];
    const int* idxs       = (const int*)d_in[4];
    const int* ptr        = (const int*)d_in[5];
    float* out            = (float*)d_out;

    unsigned short* Wb = (unsigned short*)d_ws;            // 4096*4096 bf16 = 32 MB
    unsigned short* Xb = Wb + (size_t)4096 * 4096;         // next 32 MB

    prep_kernel<<<6144, 256, 0, stream>>>(packed, scales, vals, idxs, ptr,
                                          (uint4*)Wb, x, Xb);
    gemm_bt_kernel<<<256, 512, 0, stream>>>(Xb, Wb, out);
}